// Round 12
// baseline (912.423 us; speedup 1.0000x reference)
//
#include <hip/hip_runtime.h>
#include <hip/hip_bf16.h>

// Problem constants (from reference)
#define N_NODES 50000
#define N_EDGES 1600000
#define D_FEAT  64
#define NB      391          // coarse buckets: id>>7, max id 49999 -> bucket 390
#define TILE    4096         // edges per binning block
#define NBLK    391          // ceil(N_EDGES / TILE)

// ---------------------------------------------------------------------------
// Bucket histograms for col and row (LDS-privatized; tiny global footprint)
// ---------------------------------------------------------------------------
__global__ __launch_bounds__(256) void bhist_kernel(const int* __restrict__ row,
                                                    const int* __restrict__ col,
                                                    int* __restrict__ chist,
                                                    int* __restrict__ rhist) {
    __shared__ int hc[NB], hr[NB];
    int t = threadIdx.x;
    int base = blockIdx.x * TILE;
    int n = N_EDGES - base; if (n > TILE) n = TILE;
    for (int i = t; i < NB; i += 256) { hc[i] = 0; hr[i] = 0; }
    __syncthreads();
    for (int i = t; i < n; i += 256) {
        atomicAdd(&hc[col[base + i] >> 7], 1);
        atomicAdd(&hr[row[base + i] >> 7], 1);
    }
    __syncthreads();
    for (int i = t; i < NB; i += 256) {
        if (hc[i]) atomicAdd(&chist[i], hc[i]);
        if (hr[i]) atomicAdd(&rhist[i], hr[i]);
    }
}

// ---------------------------------------------------------------------------
// Exclusive scan of both bucket histograms -> bases + cursors. 1 block.
// ---------------------------------------------------------------------------
__global__ void bucketscan_kernel(const int* __restrict__ chist, const int* __restrict__ rhist,
                                  int* __restrict__ cbase, int* __restrict__ ccur,
                                  int* __restrict__ rbase, int* __restrict__ rcur) {
    __shared__ int pc[512], pr[512];
    int t = threadIdx.x;
    int vc = (t < NB) ? chist[t] : 0;
    int vr = (t < NB) ? rhist[t] : 0;
    pc[t] = vc; pr[t] = vr;
    __syncthreads();
    for (int d = 1; d < 512; d <<= 1) {
        int xc = pc[t], xr = pr[t];
        int ac = (t >= d) ? pc[t - d] : 0;
        int ar = (t >= d) ? pr[t - d] : 0;
        __syncthreads();
        pc[t] = xc + ac; pr[t] = xr + ar;
        __syncthreads();
    }
    if (t < NB) {
        cbase[t] = pc[t] - vc; ccur[t] = pc[t] - vc;
        rbase[t] = pr[t] - vr; rcur[t] = pr[t] - vr;
    }
    if (t == NB) { cbase[NB] = N_EDGES; rbase[NB] = N_EDGES; }
}

// ---------------------------------------------------------------------------
// Bin edges: (src,col) by col-bucket into ebufC; row by row-bucket into rbuf.
// ---------------------------------------------------------------------------
__global__ __launch_bounds__(256) void bin_both_kernel(const int* __restrict__ row,
                                                       const int* __restrict__ col,
                                                       int* __restrict__ ccur, int* __restrict__ rcur,
                                                       int2* __restrict__ ebufC, int* __restrict__ rbuf) {
    __shared__ int lrow[TILE];   // 16 KB
    __shared__ int lcol[TILE];   // 16 KB
    __shared__ int hc[NB], hr[NB], cc[NB], cr[NB];
    int t = threadIdx.x;
    int base = blockIdx.x * TILE;
    int n = N_EDGES - base; if (n > TILE) n = TILE;
    for (int i = t; i < NB; i += 256) { hc[i] = 0; hr[i] = 0; }
    for (int i = t; i < n; i += 256) { lrow[i] = row[base + i]; lcol[i] = col[base + i]; }
    __syncthreads();
    for (int i = t; i < n; i += 256) {
        atomicAdd(&hc[lcol[i] >> 7], 1);
        atomicAdd(&hr[lrow[i] >> 7], 1);
    }
    __syncthreads();
    for (int i = t; i < NB; i += 256) {
        cc[i] = hc[i] ? atomicAdd(&ccur[i], hc[i]) : 0;
        cr[i] = hr[i] ? atomicAdd(&rcur[i], hr[i]) : 0;
    }
    __syncthreads();
    for (int i = t; i < n; i += 256) {
        int c = lcol[i], r = lrow[i];
        int p = atomicAdd(&cc[c >> 7], 1);
        ebufC[p] = make_int2(r, c);
        int q = atomicAdd(&cr[r >> 7], 1);
        rbuf[q] = r;
    }
}

// ---------------------------------------------------------------------------
// Per-bucket CSR: LDS 128-hist -> cnt/offs (local scan), then place esrc.
// ---------------------------------------------------------------------------
__global__ __launch_bounds__(256) void csr_bucket_kernel(const int* __restrict__ cbase,
                                                         const int2* __restrict__ ebufC,
                                                         int* __restrict__ cnt, int* __restrict__ offs,
                                                         int* __restrict__ esrc) {
    __shared__ int hist[128];
    __shared__ int pre[256];
    __shared__ int cur[128];
    int b = blockIdx.x, t = threadIdx.x;
    int s = cbase[b], e = cbase[b + 1];
    if (t < 128) hist[t] = 0;
    __syncthreads();
    for (int i = s + t; i < e; i += 256) atomicAdd(&hist[ebufC[i].y & 127], 1);
    __syncthreads();
    int v = (t < 128) ? hist[t] : 0;
    pre[t] = v;
    __syncthreads();
    for (int d = 1; d < 128; d <<= 1) {
        int x = pre[t];
        int a = (t >= d) ? pre[t - d] : 0;
        __syncthreads();
        pre[t] = x + a;
        __syncthreads();
    }
    if (t < 128) {
        int node = (b << 7) + t;
        if (node < N_NODES) {
            int off = s + pre[t] - v;
            cnt[node] = v;
            offs[node] = off;
            cur[t] = off;
        }
    }
    __syncthreads();
    for (int i = s + t; i < e; i += 256) {
        int2 d2 = ebufC[i];
        int p = atomicAdd(&cur[d2.y & 127], 1);
        esrc[p] = d2.x;
    }
}

// ---------------------------------------------------------------------------
// Per-bucket out-degree -> disf = rsqrt(deg)
// ---------------------------------------------------------------------------
__global__ __launch_bounds__(256) void deg_bucket_kernel(const int* __restrict__ rbase,
                                                         const int* __restrict__ rbuf,
                                                         float* __restrict__ disf) {
    __shared__ int hist[128];
    int b = blockIdx.x, t = threadIdx.x;
    int s = rbase[b], e = rbase[b + 1];
    if (t < 128) hist[t] = 0;
    __syncthreads();
    for (int i = s + t; i < e; i += 256) atomicAdd(&hist[rbuf[i] & 127], 1);
    __syncthreads();
    if (t < 128) {
        int node = (b << 7) + t;
        if (node < N_NODES) {
            int d = hist[t];
            disf[node] = (d > 0) ? rsqrtf((float)d) : 0.0f;
        }
    }
}

// ---------------------------------------------------------------------------
// Weight precombine + transpose: Wc0[j][k]=W0[k][j]-W2[k][j]; Wc1[j][k]=W1[k][j];
// Wc2[j][k]=2*W2[k][j]. Makes per-thread weight streams contiguous in k.
// ---------------------------------------------------------------------------
__global__ void wprep_kernel(const float* __restrict__ W, float* __restrict__ Wc) {
    int t = blockIdx.x * blockDim.x + threadIdx.x;   // 4096 threads
    int j = t & 63, k = t >> 6;
    float w0 = W[k * 64 + j];
    float w1 = W[4096 + k * 64 + j];
    float w2 = W[8192 + k * 64 + j];
    Wc[j * 64 + k]        = w0 - w2;
    Wc[4096 + j * 64 + k] = w1;
    Wc[8192 + j * 64 + k] = 2.0f * w2;
}

// ---------------------------------------------------------------------------
// Gather prop — out[n][j] = -dis[n] * sum_{e in in(n)} dis[src]*z[src][j]
// One wave per node, lane = feature, unroll-by-8 for MLP.
// ---------------------------------------------------------------------------
__global__ __launch_bounds__(256) void gather_kernel(
        const int* __restrict__ offs, const int* __restrict__ cnt,
        const int* __restrict__ esrc, const float* __restrict__ dis,
        const float* __restrict__ z, float* __restrict__ out) {
    int t  = threadIdx.x;
    int wv = t >> 6;            // wave within block: 0..3
    int j  = t & 63;            // feature
    int n  = blockIdx.x * 4 + wv;   // 12500 * 4 = 50000 exact
    int start = offs[n];
    int m     = cnt[n];
    const int* ep = esrc + start;

    float a0 = 0.f, a1 = 0.f, a2 = 0.f, a3 = 0.f;
    float a4 = 0.f, a5 = 0.f, a6 = 0.f, a7 = 0.f;
    int k = 0;
    int m8 = m & ~7;
    for (; k < m8; k += 8) {
        int s0 = ep[k + 0], s1 = ep[k + 1], s2 = ep[k + 2], s3 = ep[k + 3];
        int s4 = ep[k + 4], s5 = ep[k + 5], s6 = ep[k + 6], s7 = ep[k + 7];
        float w0 = dis[s0], w1 = dis[s1], w2 = dis[s2], w3 = dis[s3];
        float w4 = dis[s4], w5 = dis[s5], w6 = dis[s6], w7 = dis[s7];
        a0 += w0 * z[(size_t)s0 * D_FEAT + j];
        a1 += w1 * z[(size_t)s1 * D_FEAT + j];
        a2 += w2 * z[(size_t)s2 * D_FEAT + j];
        a3 += w3 * z[(size_t)s3 * D_FEAT + j];
        a4 += w4 * z[(size_t)s4 * D_FEAT + j];
        a5 += w5 * z[(size_t)s5 * D_FEAT + j];
        a6 += w6 * z[(size_t)s6 * D_FEAT + j];
        a7 += w7 * z[(size_t)s7 * D_FEAT + j];
    }
    for (; k < m; ++k) {
        int s = ep[k];
        a0 += dis[s] * z[(size_t)s * D_FEAT + j];
    }
    float acc = ((a0 + a1) + (a2 + a3)) + ((a4 + a5) + (a6 + a7));
    out[(size_t)n * D_FEAT + j] = -dis[n] * acc;
}

// ---------------------------------------------------------------------------
// Fused Chebyshev combine + bias + relu, k-vectorized (float4):
//   h[n][j] = relu( b[j] + sum_k z[n][k]*Wc0[j][k] + t1[n][k]*Wc1[j][k]
//                        + t2[n][k]*Wc2[j][k] )
// 3 independent float4 accumulators (12 chains); weights contiguous per lane.
// In-place safe (LDS staging of own rows before any write).
// ---------------------------------------------------------------------------
__global__ __launch_bounds__(256) void cheb_fused_kernel(
        const float* __restrict__ z, const float* __restrict__ t1,
        const float* __restrict__ t2, const float* __restrict__ Wc,
        const float* __restrict__ b, float* __restrict__ h) {
    __shared__ float zs[4][D_FEAT];
    __shared__ float t1s[4][D_FEAT];
    __shared__ float t2s[4][D_FEAT];
    int t  = threadIdx.x;
    int nl = t >> 6;
    int j  = t & 63;
    int node = blockIdx.x * 4 + nl;
    size_t base = (size_t)node * D_FEAT + j;
    zs[nl][j]  = z[base];
    t1s[nl][j] = t1[base];
    t2s[nl][j] = t2[base];
    __syncthreads();

    const float4* w0p = reinterpret_cast<const float4*>(Wc + j * 64);
    const float4* w1p = reinterpret_cast<const float4*>(Wc + 4096 + j * 64);
    const float4* w2p = reinterpret_cast<const float4*>(Wc + 8192 + j * 64);
    const float4* zp  = reinterpret_cast<const float4*>(zs[nl]);
    const float4* t1p = reinterpret_cast<const float4*>(t1s[nl]);
    const float4* t2p = reinterpret_cast<const float4*>(t2s[nl]);

    float4 A = make_float4(0.f, 0.f, 0.f, 0.f);
    float4 B = make_float4(0.f, 0.f, 0.f, 0.f);
    float4 C = make_float4(0.f, 0.f, 0.f, 0.f);
    #pragma unroll
    for (int q = 0; q < 16; ++q) {
        float4 w0 = w0p[q], v0 = zp[q];
        A.x += w0.x * v0.x; A.y += w0.y * v0.y; A.z += w0.z * v0.z; A.w += w0.w * v0.w;
        float4 w1 = w1p[q], v1 = t1p[q];
        B.x += w1.x * v1.x; B.y += w1.y * v1.y; B.z += w1.z * v1.z; B.w += w1.w * v1.w;
        float4 w2 = w2p[q], v2 = t2p[q];
        C.x += w2.x * v2.x; C.y += w2.y * v2.y; C.z += w2.z * v2.z; C.w += w2.w * v2.w;
    }
    float acc = b[j] + ((A.x + A.y) + (A.z + A.w))
                     + ((B.x + B.y) + (B.z + B.w))
                     + ((C.x + C.y) + (C.z + C.w));
    h[base] = fmaxf(acc, 0.0f);
}

// ---------------------------------------------------------------------------
// logits[n] = h[n] @ Wlin + blin  (64 -> 2), float32 out
// ---------------------------------------------------------------------------
__global__ void logits_kernel(const float* __restrict__ h, const float* __restrict__ Wlin,
                              const float* __restrict__ blin,
                              float* __restrict__ out) {
    int n = blockIdx.x * blockDim.x + threadIdx.x;
    if (n >= N_NODES) return;
    float a0 = blin[0];
    float a1 = blin[1];
    const float4* hr = reinterpret_cast<const float4*>(h + (size_t)n * D_FEAT);
    #pragma unroll
    for (int q = 0; q < D_FEAT / 4; ++q) {
        float4 v = hr[q];
        int j = q * 4;
        a0 += v.x * Wlin[(j + 0) * 2] + v.y * Wlin[(j + 1) * 2]
            + v.z * Wlin[(j + 2) * 2] + v.w * Wlin[(j + 3) * 2];
        a1 += v.x * Wlin[(j + 0) * 2 + 1] + v.y * Wlin[(j + 1) * 2 + 1]
            + v.z * Wlin[(j + 2) * 2 + 1] + v.w * Wlin[(j + 3) * 2 + 1];
    }
    out[n * 2 + 0] = a0;
    out[n * 2 + 1] = a1;
}

// ---------------------------------------------------------------------------
// echo edge_index into output (as float32)
// ---------------------------------------------------------------------------
__global__ void edgecopy_kernel(const int* __restrict__ ei, float* __restrict__ out) {
    int t = blockIdx.x * blockDim.x + threadIdx.x;
    if (t < 2 * N_EDGES) {
        out[t] = (float)ei[t];
    }
}

// ---------------------------------------------------------------------------
extern "C" void kernel_launch(void* const* d_in, const int* in_sizes, int n_in,
                              void* d_out, int out_size, void* d_ws, size_t ws_size,
                              hipStream_t stream) {
    const float* x    = (const float*)d_in[0];
    const int*   ei   = (const int*)d_in[1];
    const float* W1   = (const float*)d_in[2];
    const float* b1   = (const float*)d_in[3];
    const float* W2   = (const float*)d_in[4];
    const float* b2   = (const float*)d_in[5];
    const float* Wlin = (const float*)d_in[6];
    const float* blin = (const float*)d_in[7];
    float* out = (float*)d_out;      // float32 output buffer
    float* ws  = (float*)d_ws;

    const int* row = ei;             // edge_index[0] = source
    const int* col = ei + N_EDGES;   // edge_index[1] = target

    // workspace layout (4-byte units); total ~45.5 MB
    float* disf   = ws;                           // [50176]
    int*   cnt    = (int*)(ws + 50176);           // [50176]
    int*   offs   = (int*)(ws + 100352);          // [50176]
    int*   chist  = (int*)(ws + 150528);          // [512]
    int*   rhist  = (int*)(ws + 151040);          // [512]
    int*   cbase  = (int*)(ws + 151552);          // [512]
    int*   ccur   = (int*)(ws + 152064);          // [512]
    int*   rbase  = (int*)(ws + 152576);          // [512]
    int*   rcur   = (int*)(ws + 153088);          // [512]
    float* Wc1    = ws + 153600;                  // [12288]
    float* Wc2    = ws + 165888;                  // [12288]
    int*   esrc   = (int*)(ws + 178176);          // [1600000]
    float* T1     = ws + 1778176;                 // [3.2M]
    float* T2     = ws + 4978176;                 // [3.2M]
    float* H      = ws + 8178176;                 // [3.2M]
    int*   rbuf   = (int*)T1;                     // aliases T1 (dead before gathers)
    int2*  ebufC  = (int2*)T2;                    // aliases T2 (byte offset % 8 == 0)

    // --- CSR build (no global scattered atomics) + weight prep ---
    hipMemsetAsync(chist, 0, 1024 * sizeof(int), stream);   // chist + rhist
    bhist_kernel<<<NBLK, 256, 0, stream>>>(row, col, chist, rhist);
    bucketscan_kernel<<<1, 512, 0, stream>>>(chist, rhist, cbase, ccur, rbase, rcur);
    bin_both_kernel<<<NBLK, 256, 0, stream>>>(row, col, ccur, rcur, ebufC, rbuf);
    csr_bucket_kernel<<<NB, 256, 0, stream>>>(cbase, ebufC, cnt, offs, esrc);
    deg_bucket_kernel<<<NB, 256, 0, stream>>>(rbase, rbuf, disf);
    wprep_kernel<<<16, 256, 0, stream>>>(W1, Wc1);
    wprep_kernel<<<16, 256, 0, stream>>>(W2, Wc2);

    const int gatherBlocks = N_NODES / 4;   // 12500

    // --- layer 1 ---
    gather_kernel<<<gatherBlocks, 256, 0, stream>>>(offs, cnt, esrc, disf, x, T1);
    gather_kernel<<<gatherBlocks, 256, 0, stream>>>(offs, cnt, esrc, disf, T1, T2);
    cheb_fused_kernel<<<gatherBlocks, 256, 0, stream>>>(x, T1, T2, Wc1, b1, H);

    // --- layer 2 ---
    gather_kernel<<<gatherBlocks, 256, 0, stream>>>(offs, cnt, esrc, disf, H, T1);
    gather_kernel<<<gatherBlocks, 256, 0, stream>>>(offs, cnt, esrc, disf, T1, T2);
    cheb_fused_kernel<<<gatherBlocks, 256, 0, stream>>>(H, T1, T2, Wc2, b2, H); // in-place safe

    // --- head ---
    logits_kernel<<<(N_NODES + 255) / 256, 256, 0, stream>>>(H, Wlin, blin, out);
    edgecopy_kernel<<<(2 * N_EDGES + 255) / 256, 256, 0, stream>>>(ei, out + (size_t)N_NODES * 2);
}

// Round 13
// 542.170 us; speedup vs baseline: 1.6829x; 1.6829x over previous
//
#include <hip/hip_runtime.h>
#include <hip/hip_bf16.h>

// Problem constants (from reference)
#define N_NODES 50000
#define N_EDGES 1600000
#define D_FEAT  64
#define NB      391          // coarse buckets: id>>7, max id 49999 -> bucket 390
#define TILE    4096         // edges per binning block
#define NBLK    391          // ceil(N_EDGES / TILE)

// ---------------------------------------------------------------------------
// Bucket histograms for col and row (LDS-privatized; tiny global footprint)
// ---------------------------------------------------------------------------
__global__ __launch_bounds__(256) void bhist_kernel(const int* __restrict__ row,
                                                    const int* __restrict__ col,
                                                    int* __restrict__ chist,
                                                    int* __restrict__ rhist) {
    __shared__ int hc[NB], hr[NB];
    int t = threadIdx.x;
    int base = blockIdx.x * TILE;
    int n = N_EDGES - base; if (n > TILE) n = TILE;
    for (int i = t; i < NB; i += 256) { hc[i] = 0; hr[i] = 0; }
    __syncthreads();
    for (int i = t; i < n; i += 256) {
        atomicAdd(&hc[col[base + i] >> 7], 1);
        atomicAdd(&hr[row[base + i] >> 7], 1);
    }
    __syncthreads();
    for (int i = t; i < NB; i += 256) {
        if (hc[i]) atomicAdd(&chist[i], hc[i]);
        if (hr[i]) atomicAdd(&rhist[i], hr[i]);
    }
}

// ---------------------------------------------------------------------------
// Exclusive scan of both bucket histograms -> bases + cursors. 1 block.
// ---------------------------------------------------------------------------
__global__ void bucketscan_kernel(const int* __restrict__ chist, const int* __restrict__ rhist,
                                  int* __restrict__ cbase, int* __restrict__ ccur,
                                  int* __restrict__ rbase, int* __restrict__ rcur) {
    __shared__ int pc[512], pr[512];
    int t = threadIdx.x;
    int vc = (t < NB) ? chist[t] : 0;
    int vr = (t < NB) ? rhist[t] : 0;
    pc[t] = vc; pr[t] = vr;
    __syncthreads();
    for (int d = 1; d < 512; d <<= 1) {
        int xc = pc[t], xr = pr[t];
        int ac = (t >= d) ? pc[t - d] : 0;
        int ar = (t >= d) ? pr[t - d] : 0;
        __syncthreads();
        pc[t] = xc + ac; pr[t] = xr + ar;
        __syncthreads();
    }
    if (t < NB) {
        cbase[t] = pc[t] - vc; ccur[t] = pc[t] - vc;
        rbase[t] = pr[t] - vr; rcur[t] = pr[t] - vr;
    }
    if (t == NB) { cbase[NB] = N_EDGES; rbase[NB] = N_EDGES; }
}

// ---------------------------------------------------------------------------
// Bin edges: (src,col) by col-bucket into ebufC; row by row-bucket into rbuf.
// ---------------------------------------------------------------------------
__global__ __launch_bounds__(256) void bin_both_kernel(const int* __restrict__ row,
                                                       const int* __restrict__ col,
                                                       int* __restrict__ ccur, int* __restrict__ rcur,
                                                       int2* __restrict__ ebufC, int* __restrict__ rbuf) {
    __shared__ int lrow[TILE];   // 16 KB
    __shared__ int lcol[TILE];   // 16 KB
    __shared__ int hc[NB], hr[NB], cc[NB], cr[NB];
    int t = threadIdx.x;
    int base = blockIdx.x * TILE;
    int n = N_EDGES - base; if (n > TILE) n = TILE;
    for (int i = t; i < NB; i += 256) { hc[i] = 0; hr[i] = 0; }
    for (int i = t; i < n; i += 256) { lrow[i] = row[base + i]; lcol[i] = col[base + i]; }
    __syncthreads();
    for (int i = t; i < n; i += 256) {
        atomicAdd(&hc[lcol[i] >> 7], 1);
        atomicAdd(&hr[lrow[i] >> 7], 1);
    }
    __syncthreads();
    for (int i = t; i < NB; i += 256) {
        cc[i] = hc[i] ? atomicAdd(&ccur[i], hc[i]) : 0;
        cr[i] = hr[i] ? atomicAdd(&rcur[i], hr[i]) : 0;
    }
    __syncthreads();
    for (int i = t; i < n; i += 256) {
        int c = lcol[i], r = lrow[i];
        int p = atomicAdd(&cc[c >> 7], 1);
        ebufC[p] = make_int2(r, c);
        int q = atomicAdd(&cr[r >> 7], 1);
        rbuf[q] = r;
    }
}

// ---------------------------------------------------------------------------
// Per-bucket CSR: LDS 128-hist -> cnt/offs (local scan), then place esrc.
// ---------------------------------------------------------------------------
__global__ __launch_bounds__(256) void csr_bucket_kernel(const int* __restrict__ cbase,
                                                         const int2* __restrict__ ebufC,
                                                         int* __restrict__ cnt, int* __restrict__ offs,
                                                         int* __restrict__ esrc) {
    __shared__ int hist[128];
    __shared__ int pre[256];
    __shared__ int cur[128];
    int b = blockIdx.x, t = threadIdx.x;
    int s = cbase[b], e = cbase[b + 1];
    if (t < 128) hist[t] = 0;
    __syncthreads();
    for (int i = s + t; i < e; i += 256) atomicAdd(&hist[ebufC[i].y & 127], 1);
    __syncthreads();
    int v = (t < 128) ? hist[t] : 0;
    pre[t] = v;
    __syncthreads();
    for (int d = 1; d < 128; d <<= 1) {
        int x = pre[t];
        int a = (t >= d) ? pre[t - d] : 0;
        __syncthreads();
        pre[t] = x + a;
        __syncthreads();
    }
    if (t < 128) {
        int node = (b << 7) + t;
        if (node < N_NODES) {
            int off = s + pre[t] - v;
            cnt[node] = v;
            offs[node] = off;
            cur[t] = off;
        }
    }
    __syncthreads();
    for (int i = s + t; i < e; i += 256) {
        int2 d2 = ebufC[i];
        int p = atomicAdd(&cur[d2.y & 127], 1);
        esrc[p] = d2.x;
    }
}

// ---------------------------------------------------------------------------
// Per-bucket out-degree -> disf = rsqrt(deg)
// ---------------------------------------------------------------------------
__global__ __launch_bounds__(256) void deg_bucket_kernel(const int* __restrict__ rbase,
                                                         const int* __restrict__ rbuf,
                                                         float* __restrict__ disf) {
    __shared__ int hist[128];
    int b = blockIdx.x, t = threadIdx.x;
    int s = rbase[b], e = rbase[b + 1];
    if (t < 128) hist[t] = 0;
    __syncthreads();
    for (int i = s + t; i < e; i += 256) atomicAdd(&hist[rbuf[i] & 127], 1);
    __syncthreads();
    if (t < 128) {
        int node = (b << 7) + t;
        if (node < N_NODES) {
            int d = hist[t];
            disf[node] = (d > 0) ? rsqrtf((float)d) : 0.0f;
        }
    }
}

// ---------------------------------------------------------------------------
// Weight precombine (NO transpose — keep coalesced [k][j] orientation):
// Wc0[k][j]=W0-W2; Wc1[k][j]=W1; Wc2[k][j]=2*W2
// ---------------------------------------------------------------------------
__global__ void wprep_kernel(const float* __restrict__ W, float* __restrict__ Wc) {
    int t = blockIdx.x * blockDim.x + threadIdx.x;   // 4096 threads
    float w0 = W[t];
    float w1 = W[4096 + t];
    float w2 = W[8192 + t];
    Wc[t]        = w0 - w2;
    Wc[4096 + t] = w1;
    Wc[8192 + t] = 2.0f * w2;
}

// ---------------------------------------------------------------------------
// Gather prop — out[n][j] = -dis[n] * sum_{e in in(n)} dis[src]*z[src][j]
// 2 nodes per wave: half-wave (32 lanes) per node, float2 per lane.
// 16 outstanding row-streams per wave. Unroll-by-8.
// ---------------------------------------------------------------------------
__global__ __launch_bounds__(256) void gather_kernel(
        const int* __restrict__ offs, const int* __restrict__ cnt,
        const int* __restrict__ esrc, const float* __restrict__ dis,
        const float* __restrict__ z, float* __restrict__ out) {
    int t    = threadIdx.x;
    int wv   = t >> 6;                 // wave in block: 0..3
    int lane = t & 63;
    int half = lane >> 5;              // 0/1: node within wave
    int jj   = (lane & 31) * 2;        // feature pair
    int n = blockIdx.x * 8 + wv * 2 + half;   // 6250*8 = 50000 exact
    int start = offs[n];
    int m     = cnt[n];
    const int* ep = esrc + start;

    float2 a0 = {0.f,0.f}, a1 = {0.f,0.f}, a2 = {0.f,0.f}, a3 = {0.f,0.f};
    float2 a4 = {0.f,0.f}, a5 = {0.f,0.f}, a6 = {0.f,0.f}, a7 = {0.f,0.f};
    int k = 0;
    int m8 = m & ~7;
    for (; k < m8; k += 8) {
        int s0 = ep[k + 0], s1 = ep[k + 1], s2 = ep[k + 2], s3 = ep[k + 3];
        int s4 = ep[k + 4], s5 = ep[k + 5], s6 = ep[k + 6], s7 = ep[k + 7];
        float w0 = dis[s0], w1 = dis[s1], w2 = dis[s2], w3 = dis[s3];
        float w4 = dis[s4], w5 = dis[s5], w6 = dis[s6], w7 = dis[s7];
        float2 v0 = *reinterpret_cast<const float2*>(z + (size_t)s0 * D_FEAT + jj);
        float2 v1 = *reinterpret_cast<const float2*>(z + (size_t)s1 * D_FEAT + jj);
        float2 v2 = *reinterpret_cast<const float2*>(z + (size_t)s2 * D_FEAT + jj);
        float2 v3 = *reinterpret_cast<const float2*>(z + (size_t)s3 * D_FEAT + jj);
        float2 v4 = *reinterpret_cast<const float2*>(z + (size_t)s4 * D_FEAT + jj);
        float2 v5 = *reinterpret_cast<const float2*>(z + (size_t)s5 * D_FEAT + jj);
        float2 v6 = *reinterpret_cast<const float2*>(z + (size_t)s6 * D_FEAT + jj);
        float2 v7 = *reinterpret_cast<const float2*>(z + (size_t)s7 * D_FEAT + jj);
        a0.x += w0 * v0.x; a0.y += w0 * v0.y;
        a1.x += w1 * v1.x; a1.y += w1 * v1.y;
        a2.x += w2 * v2.x; a2.y += w2 * v2.y;
        a3.x += w3 * v3.x; a3.y += w3 * v3.y;
        a4.x += w4 * v4.x; a4.y += w4 * v4.y;
        a5.x += w5 * v5.x; a5.y += w5 * v5.y;
        a6.x += w6 * v6.x; a6.y += w6 * v6.y;
        a7.x += w7 * v7.x; a7.y += w7 * v7.y;
    }
    for (; k < m; ++k) {
        int s = ep[k];
        float w = dis[s];
        float2 v = *reinterpret_cast<const float2*>(z + (size_t)s * D_FEAT + jj);
        a0.x += w * v.x; a0.y += w * v.y;
    }
    float ax = ((a0.x + a1.x) + (a2.x + a3.x)) + ((a4.x + a5.x) + (a6.x + a7.x));
    float ay = ((a0.y + a1.y) + (a2.y + a3.y)) + ((a4.y + a5.y) + (a6.y + a7.y));
    float s = -dis[n];
    float2 r; r.x = s * ax; r.y = s * ay;
    *reinterpret_cast<float2*>(out + (size_t)n * D_FEAT + jj) = r;
}

// ---------------------------------------------------------------------------
// Fused Chebyshev combine + bias + relu. ONE WAVE PER NODE (64-thr blocks):
// A-row pointers are blockIdx-derived -> provably scalar -> s_load (SMEM
// pipe), weights read coalesced [k][j] (L1-broadcast shared by all waves).
// No LDS, no syncthreads; per-wave in-place safety.
//   h[n][j] = relu( b[j] + sum_k z[n][k]*Wc0[k][j] + t1[n][k]*Wc1[k][j]
//                        + t2[n][k]*Wc2[k][j] )
// ---------------------------------------------------------------------------
__global__ __launch_bounds__(64) void cheb_fused_kernel(
        const float* __restrict__ z, const float* __restrict__ t1,
        const float* __restrict__ t2, const float* __restrict__ Wc,
        const float* __restrict__ b, float* __restrict__ h) {
    int j = threadIdx.x;
    int n = blockIdx.x;
    const float* zn  = z  + (size_t)n * D_FEAT;
    const float* t1n = t1 + (size_t)n * D_FEAT;
    const float* t2n = t2 + (size_t)n * D_FEAT;
    const float* W0 = Wc + j;
    const float* W1 = Wc + 4096 + j;
    const float* W2 = Wc + 8192 + j;

    float acc0 = b[j], acc1 = 0.f, acc2 = 0.f;
    #pragma unroll
    for (int k = 0; k < D_FEAT; ++k) {
        acc0 += zn[k]  * W0[k * 64];
        acc1 += t1n[k] * W1[k * 64];
        acc2 += t2n[k] * W2[k * 64];
    }
    h[(size_t)n * D_FEAT + j] = fmaxf(acc0 + acc1 + acc2, 0.0f);
}

// ---------------------------------------------------------------------------
// logits[n] = h[n] @ Wlin + blin  (64 -> 2), float32 out
// ---------------------------------------------------------------------------
__global__ void logits_kernel(const float* __restrict__ h, const float* __restrict__ Wlin,
                              const float* __restrict__ blin,
                              float* __restrict__ out) {
    int n = blockIdx.x * blockDim.x + threadIdx.x;
    if (n >= N_NODES) return;
    float a0 = blin[0];
    float a1 = blin[1];
    const float4* hr = reinterpret_cast<const float4*>(h + (size_t)n * D_FEAT);
    #pragma unroll
    for (int q = 0; q < D_FEAT / 4; ++q) {
        float4 v = hr[q];
        int j = q * 4;
        a0 += v.x * Wlin[(j + 0) * 2] + v.y * Wlin[(j + 1) * 2]
            + v.z * Wlin[(j + 2) * 2] + v.w * Wlin[(j + 3) * 2];
        a1 += v.x * Wlin[(j + 0) * 2 + 1] + v.y * Wlin[(j + 1) * 2 + 1]
            + v.z * Wlin[(j + 2) * 2 + 1] + v.w * Wlin[(j + 3) * 2 + 1];
    }
    out[n * 2 + 0] = a0;
    out[n * 2 + 1] = a1;
}

// ---------------------------------------------------------------------------
// echo edge_index into output (as float32)
// ---------------------------------------------------------------------------
__global__ void edgecopy_kernel(const int* __restrict__ ei, float* __restrict__ out) {
    int t = blockIdx.x * blockDim.x + threadIdx.x;
    if (t < 2 * N_EDGES) {
        out[t] = (float)ei[t];
    }
}

// ---------------------------------------------------------------------------
extern "C" void kernel_launch(void* const* d_in, const int* in_sizes, int n_in,
                              void* d_out, int out_size, void* d_ws, size_t ws_size,
                              hipStream_t stream) {
    const float* x    = (const float*)d_in[0];
    const int*   ei   = (const int*)d_in[1];
    const float* W1   = (const float*)d_in[2];
    const float* b1   = (const float*)d_in[3];
    const float* W2   = (const float*)d_in[4];
    const float* b2   = (const float*)d_in[5];
    const float* Wlin = (const float*)d_in[6];
    const float* blin = (const float*)d_in[7];
    float* out = (float*)d_out;      // float32 output buffer
    float* ws  = (float*)d_ws;

    const int* row = ei;             // edge_index[0] = source
    const int* col = ei + N_EDGES;   // edge_index[1] = target

    // workspace layout (4-byte units); total ~45.5 MB
    float* disf   = ws;                           // [50176]
    int*   cnt    = (int*)(ws + 50176);           // [50176]
    int*   offs   = (int*)(ws + 100352);          // [50176]
    int*   chist  = (int*)(ws + 150528);          // [512]
    int*   rhist  = (int*)(ws + 151040);          // [512]
    int*   cbase  = (int*)(ws + 151552);          // [512]
    int*   ccur   = (int*)(ws + 152064);          // [512]
    int*   rbase  = (int*)(ws + 152576);          // [512]
    int*   rcur   = (int*)(ws + 153088);          // [512]
    float* Wc1    = ws + 153600;                  // [12288]
    float* Wc2    = ws + 165888;                  // [12288]
    int*   esrc   = (int*)(ws + 178176);          // [1600000]
    float* T1     = ws + 1778176;                 // [3.2M]
    float* T2     = ws + 4978176;                 // [3.2M]
    float* H      = ws + 8178176;                 // [3.2M]
    int*   rbuf   = (int*)T1;                     // aliases T1 (dead before gathers)
    int2*  ebufC  = (int2*)T2;                    // aliases T2 (byte offset % 8 == 0)

    // --- CSR build (no global scattered atomics) + weight prep ---
    hipMemsetAsync(chist, 0, 1024 * sizeof(int), stream);   // chist + rhist
    bhist_kernel<<<NBLK, 256, 0, stream>>>(row, col, chist, rhist);
    bucketscan_kernel<<<1, 512, 0, stream>>>(chist, rhist, cbase, ccur, rbase, rcur);
    bin_both_kernel<<<NBLK, 256, 0, stream>>>(row, col, ccur, rcur, ebufC, rbuf);
    csr_bucket_kernel<<<NB, 256, 0, stream>>>(cbase, ebufC, cnt, offs, esrc);
    deg_bucket_kernel<<<NB, 256, 0, stream>>>(rbase, rbuf, disf);
    wprep_kernel<<<16, 256, 0, stream>>>(W1, Wc1);
    wprep_kernel<<<16, 256, 0, stream>>>(W2, Wc2);

    const int gatherBlocks = N_NODES / 8;   // 6250

    // --- layer 1 ---
    gather_kernel<<<gatherBlocks, 256, 0, stream>>>(offs, cnt, esrc, disf, x, T1);
    gather_kernel<<<gatherBlocks, 256, 0, stream>>>(offs, cnt, esrc, disf, T1, T2);
    cheb_fused_kernel<<<N_NODES, 64, 0, stream>>>(x, T1, T2, Wc1, b1, H);

    // --- layer 2 ---
    gather_kernel<<<gatherBlocks, 256, 0, stream>>>(offs, cnt, esrc, disf, H, T1);
    gather_kernel<<<gatherBlocks, 256, 0, stream>>>(offs, cnt, esrc, disf, T1, T2);
    cheb_fused_kernel<<<N_NODES, 64, 0, stream>>>(H, T1, T2, Wc2, b2, H); // in-place safe

    // --- head ---
    logits_kernel<<<(N_NODES + 255) / 256, 256, 0, stream>>>(H, Wlin, blin, out);
    edgecopy_kernel<<<(2 * N_EDGES + 255) / 256, 256, 0, stream>>>(ei, out + (size_t)N_NODES * 2);
}